// Round 19
// baseline (54.472 us; speedup 1.0000x reference)
//
#include <hip/hip_runtime.h>

// LNCC loss: I,J [16,1,768,768] f32 -> out [16] f32
// R19 = R17 (best kernel 40.2us: depth-2 in-prefetch, depth-1 out-prefetch,
// 2-row chunks, shuffle hsum, 124 VGPR) + two changes:
// (1) __builtin_amdgcn_sched_barrier(0) after every load group: at 124-VGPR
//     pressure the scheduler sinks loads toward uses (shorter live ranges),
//     silently collapsing the software pipeline; the fence pins issue order
//     so depth-2 (~2240cy compute between issue and use) actually covers the
//     ~900cy HBM-cold latency (harness fills evict L3 between replays).
// (2) no atomics: blocks write partials to ws[b*64+seg]; zero_acc kernel
//     deleted; finalize is a 16-wave block reduce. Saves ~1.5-2us of scored
//     total (aux kernels were ~3us of R14's 42.4).

constexpr int BATCH = 16;
constexpr int H = 768;
constexpr int W = 768;
constexpr float INV_WS = 1.0f / 81.0f;
constexpr float EPS = 3.0590232050182579e-07f;   // exp(-15)

constexpr int SEG = 12;                   // output rows per wave task
constexpr int NSEG = H / SEG;             // 64
constexpr int BANDW = 248;                // output cols per band
constexpr int NTHREADS = 256;             // 4 waves = 4 bands of one (seg,b)

#define F4ADD(a, u)    { a.x += u.x; a.y += u.y; a.z += u.z; a.w += u.w; }
#define F4SUB(a, u)    { a.x -= u.x; a.y -= u.y; a.z -= u.z; a.w -= u.w; }
#define F4FMA(a, u, v) { a.x = fmaf(u.x, v.x, a.x); a.y = fmaf(u.y, v.y, a.y); \
                         a.z = fmaf(u.z, v.z, a.z); a.w = fmaf(u.w, v.w, a.w); }
#define F4FMS(a, u, v) { a.x = fmaf(u.x, -v.x, a.x); a.y = fmaf(u.y, -v.y, a.y); \
                         a.z = fmaf(u.z, -v.z, a.z); a.w = fmaf(u.w, -v.w, a.w); }

// h[e] = sum of cs cols [c0+e, c0+e+8]; output col = c0+4+e = band*248+4*lane+e
#define HSUM_SHFL(c, h)                                                   \
    {                                                                     \
        const float s3 = c.w;                                             \
        const float s2 = c.w + c.z;                                       \
        const float s1 = s2 + c.y;                                        \
        const float s0 = s1 + c.x;          /* own total */               \
        const float p1 = c.x + c.y;                                       \
        const float p2 = p1 + c.z;                                        \
        const float pn = __shfl_down(s0, 1, 64);                          \
        const float q0 = __shfl_down(c.x, 2, 64);                         \
        const float q1 = __shfl_down(p1, 2, 64);                          \
        const float q2 = __shfl_down(p2, 2, 64);                          \
        const float q3 = __shfl_down(s0, 2, 64);                          \
        h[0] = s0 + pn + q0;                                              \
        h[1] = s1 + pn + q1;                                              \
        h[2] = s2 + pn + q2;                                              \
        h[3] = s3 + pn + q3;                                              \
    }

// load 2 rows (rbase, rbase+1) PRE-MASKED: addr clamped, value scaled by
// (row in [0,H) ? fm : 0); each loaded row is consumed exactly once.
#define LD2(NI, NJ, rbase)                                                \
    {                                                                     \
        _Pragma("unroll")                                                 \
        for (int k = 0; k < 2; ++k) {                                     \
            const int rr = (rbase) + k;                                   \
            const int rc = min(max(rr, 0), H - 1);                        \
            const float mk = (rr >= 0 && rr < H) ? fm : 0.0f;             \
            float4 ti = *(const float4*)(Ib + (size_t)rc * W + ca);       \
            float4 tj = *(const float4*)(Jb + (size_t)rc * W + ca);       \
            ti.x *= mk; ti.y *= mk; ti.z *= mk; ti.w *= mk;               \
            tj.x *= mk; tj.y *= mk; tj.z *= mk; tj.w *= mk;               \
            NI[k] = ti; NJ[k] = tj;                                       \
        }                                                                 \
    }

#define PIN() __builtin_amdgcn_sched_barrier(0);

// compute 2 output rows from pre-masked in-batch (VI,VJ) and out-batch (OI,OJ)
#define CHUNK(VI, VJ, OI, OJ)                                             \
    _Pragma("unroll")                                                     \
    for (int k = 0; k < 2; ++k) {                                         \
        F4ADD(cs0, VI[k]) F4ADD(cs1, VJ[k])                               \
        F4FMA(cs2, VI[k], VI[k]) F4FMA(cs3, VJ[k], VJ[k])                 \
        F4FMA(cs4, VI[k], VJ[k])                                          \
        float hI[4], hJ[4], hII[4], hJJ[4], hIJ[4];                       \
        HSUM_SHFL(cs0, hI)                                                \
        HSUM_SHFL(cs1, hJ)                                                \
        HSUM_SHFL(cs2, hII)                                               \
        HSUM_SHFL(cs3, hJJ)                                               \
        HSUM_SHFL(cs4, hIJ)                                               \
        float rowsum = 0.0f;                                              \
        _Pragma("unroll")                                                 \
        for (int e = 0; e < 4; ++e) {                                     \
            const float u = -hI[e] * INV_WS;                              \
            const float cross = fmaf(u, hJ[e], hIJ[e]);                   \
            const float Ivar  = fmaf(u, hI[e], hII[e]);                   \
            const float Jvar  = fmaf(-hJ[e] * INV_WS, hJ[e], hJJ[e]);     \
            float prod = Ivar * Jvar;                                     \
            float num  = cross * cross;                                   \
            if (!(prod > EPS)) { prod = 1.0f; num = 1.0f; }               \
            float inv_;                                                   \
            asm("v_rcp_f32 %0, %1" : "=v"(inv_) : "v"(prod + EPS));       \
            rowsum = fmaf(num, inv_, rowsum);                             \
        }                                                                 \
        accum += live ? rowsum : 0.0f;                                    \
        F4SUB(cs0, OI[k]) F4SUB(cs1, OJ[k])                               \
        F4FMS(cs2, OI[k], OI[k]) F4FMS(cs3, OJ[k], OJ[k])                 \
        F4FMS(cs4, OI[k], OJ[k])                                          \
    }

__launch_bounds__(NTHREADS, 2)
__global__ void lncc_pin(const float* __restrict__ gI, const float* __restrict__ gJ,
                         float* __restrict__ part)
{
    __shared__ float wsum[4];

    const int lane = threadIdx.x & 63;
    const int band = threadIdx.x >> 6;                   // 0..3
    const int r0   = blockIdx.x * SEG;
    const int b    = blockIdx.y;
    const int c0   = band * BANDW - 4 + 4 * lane;        // own cs base col
    const float fm = (c0 >= 0 && c0 + 3 < W) ? 1.0f : 0.0f;
    const int ca   = min(max(c0, 0), W - 4);             // 16B-aligned clamp
    const bool live = (lane <= 61) && (band * BANDW + 4 * lane + 3 < W);

    const float* __restrict__ Ib = gI + (size_t)b * (H * W);
    const float* __restrict__ Jb = gJ + (size_t)b * (H * W);

    float4 cs0 = {0,0,0,0}, cs1 = {0,0,0,0}, cs2 = {0,0,0,0},
           cs3 = {0,0,0,0}, cs4 = {0,0,0,0};

    // ---- warm-up: 4 pre-masked 2-row chunks (rows r0-4 .. r0+3) ----
    float4 W0i[2], W0j[2], W1i[2], W1j[2], W2i[2], W2j[2], W3i[2], W3j[2];
    LD2(W0i, W0j, r0 - 4)
    LD2(W1i, W1j, r0 - 2)
    LD2(W2i, W2j, r0)
    LD2(W3i, W3j, r0 + 2)

    // ---- pipeline preload: in-chunks 0,1 (depth 2) + out-chunk 0 ----
    float4 I0i[2], I0j[2], I1i[2], I1j[2], I2i[2], I2j[2];
    float4 I3i[2], I3j[2], I4i[2], I4j[2], I5i[2], I5j[2];
    float4 OAi[2], OAj[2], OBi[2], OBj[2];
    LD2(I0i, I0j, r0 + 4)
    LD2(I1i, I1j, r0 + 6)
    LD2(OAi, OAj, r0 - 4)
    PIN()

    // warm-up accumulate (~700 cy) covers the preload latency
#define WACC(WI, WJ)                                                      \
    _Pragma("unroll")                                                     \
    for (int k = 0; k < 2; ++k) {                                         \
        F4ADD(cs0, WI[k]) F4ADD(cs1, WJ[k])                               \
        F4FMA(cs2, WI[k], WI[k]) F4FMA(cs3, WJ[k], WJ[k])                 \
        F4FMA(cs4, WI[k], WJ[k])                                          \
    }
    WACC(W0i, W0j) WACC(W1i, W1j) WACC(W2i, W2j) WACC(W3i, W3j)
#undef WACC

    float accum = 0.0f;

    // ---- 6 pipelined chunks of 2 rows (SEG = 12) ----
    // in-loads issued 2 chunks ahead, out-loads 1 chunk ahead; PIN() forbids
    // the scheduler from sinking the loads into/past the chunk compute.
    LD2(I2i, I2j, r0 + 8)   LD2(OBi, OBj, r0 - 2)   PIN()  CHUNK(I0i, I0j, OAi, OAj)
    LD2(I3i, I3j, r0 + 10)  LD2(OAi, OAj, r0)       PIN()  CHUNK(I1i, I1j, OBi, OBj)
    LD2(I4i, I4j, r0 + 12)  LD2(OBi, OBj, r0 + 2)   PIN()  CHUNK(I2i, I2j, OAi, OAj)
    LD2(I5i, I5j, r0 + 14)  LD2(OAi, OAj, r0 + 4)   PIN()  CHUNK(I3i, I3j, OBi, OBj)
                            LD2(OBi, OBj, r0 + 6)   PIN()  CHUNK(I4i, I4j, OAi, OAj)
                                                           CHUNK(I5i, I5j, OBi, OBj)

    // ---- wave reduce -> block reduce -> one partial-store per block ----
    #pragma unroll
    for (int off = 32; off > 0; off >>= 1)
        accum += __shfl_xor(accum, off, 64);
    if (lane == 0) wsum[band] = accum;
    __syncthreads();
    if (threadIdx.x == 0)
        part[blockIdx.y * NSEG + blockIdx.x] = wsum[0] + wsum[1] + wsum[2] + wsum[3];
}

// one wave per batch image: reduce 64 block-partials, write final loss
__global__ void finalize2(const float* __restrict__ part, float* __restrict__ out) {
    const int b = threadIdx.y;              // 0..15 (one wave each)
    const int x = threadIdx.x;              // 0..63
    float v = part[b * NSEG + x];
    #pragma unroll
    for (int off = 32; off > 0; off >>= 1)
        v += __shfl_xor(v, off, 64);
    if (x == 0)
        out[b] = 1.0f - v * (1.0f / (float)(H * W));
}

extern "C" void kernel_launch(void* const* d_in, const int* in_sizes, int n_in,
                              void* d_out, int out_size, void* d_ws, size_t ws_size,
                              hipStream_t stream) {
    const float* I = (const float*)d_in[0];
    const float* J = (const float*)d_in[1];
    float* out  = (float*)d_out;
    float* part = (float*)d_ws;             // 16*64 floats, fully overwritten

    dim3 grid(NSEG, BATCH);   // 64 x 16 = 1024 blocks = 4/CU, 16 waves/CU
    lncc_pin<<<grid, NTHREADS, 0, stream>>>(I, J, part);

    finalize2<<<1, dim3(64, BATCH), 0, stream>>>(part, out);
}

// Round 20
// 36.953 us; speedup vs baseline: 1.4741x; 1.4741x over previous
//
#include <hip/hip_runtime.h>

// LNCC loss: I,J [16,1,768,768] f32 -> out [16] f32
// R20 = R17's hot kernel EXACTLY (best: 40.2us kernel, 124 VGPR, depth-2
// in-prefetch / depth-1 out-prefetch 2-row-chunk pipeline, shuffle hsum,
// no sched_barrier — R19 proved PIN() causes regalloc spill: 51MB writes).
// Only the epilogue changes: per-block partial stores into d_ws replace
// {zero_acc kernel + atomicAdd}, and finalize2 (16 waves, one per image)
// reduces the 64 partials. Reclaims ~2us of the ~3us aux overhead seen
// between kernel dur (39-40) and scored dur (42-43) in R14/R17.

constexpr int BATCH = 16;
constexpr int H = 768;
constexpr int W = 768;
constexpr float INV_WS = 1.0f / 81.0f;
constexpr float EPS = 3.0590232050182579e-07f;   // exp(-15)

constexpr int SEG = 12;                   // output rows per wave task
constexpr int NSEG = H / SEG;             // 64
constexpr int BANDW = 248;                // output cols per band
constexpr int NTHREADS = 256;             // 4 waves = 4 bands of one (seg,b)

#define F4ADD(a, u)    { a.x += u.x; a.y += u.y; a.z += u.z; a.w += u.w; }
#define F4SUB(a, u)    { a.x -= u.x; a.y -= u.y; a.z -= u.z; a.w -= u.w; }
#define F4FMA(a, u, v) { a.x = fmaf(u.x, v.x, a.x); a.y = fmaf(u.y, v.y, a.y); \
                         a.z = fmaf(u.z, v.z, a.z); a.w = fmaf(u.w, v.w, a.w); }
#define F4FMS(a, u, v) { a.x = fmaf(u.x, -v.x, a.x); a.y = fmaf(u.y, -v.y, a.y); \
                         a.z = fmaf(u.z, -v.z, a.z); a.w = fmaf(u.w, -v.w, a.w); }

// h[e] = sum of cs cols [c0+e, c0+e+8]; output col = c0+4+e = band*248+4*lane+e
#define HSUM_SHFL(c, h)                                                   \
    {                                                                     \
        const float s3 = c.w;                                             \
        const float s2 = c.w + c.z;                                       \
        const float s1 = s2 + c.y;                                        \
        const float s0 = s1 + c.x;          /* own total */               \
        const float p1 = c.x + c.y;                                      \
        const float p2 = p1 + c.z;                                        \
        const float pn = __shfl_down(s0, 1, 64);                          \
        const float q0 = __shfl_down(c.x, 2, 64);                         \
        const float q1 = __shfl_down(p1, 2, 64);                          \
        const float q2 = __shfl_down(p2, 2, 64);                          \
        const float q3 = __shfl_down(s0, 2, 64);                          \
        h[0] = s0 + pn + q0;                                              \
        h[1] = s1 + pn + q1;                                              \
        h[2] = s2 + pn + q2;                                              \
        h[3] = s3 + pn + q3;                                              \
    }

// load 2 rows (rbase, rbase+1) PRE-MASKED: addr clamped, value scaled by
// (row in [0,H) ? fm : 0); each loaded row is consumed exactly once.
#define LD2(NI, NJ, rbase)                                                \
    {                                                                     \
        _Pragma("unroll")                                                 \
        for (int k = 0; k < 2; ++k) {                                     \
            const int rr = (rbase) + k;                                   \
            const int rc = min(max(rr, 0), H - 1);                        \
            const float mk = (rr >= 0 && rr < H) ? fm : 0.0f;             \
            float4 ti = *(const float4*)(Ib + (size_t)rc * W + ca);       \
            float4 tj = *(const float4*)(Jb + (size_t)rc * W + ca);       \
            ti.x *= mk; ti.y *= mk; ti.z *= mk; ti.w *= mk;               \
            tj.x *= mk; tj.y *= mk; tj.z *= mk; tj.w *= mk;               \
            NI[k] = ti; NJ[k] = tj;                                       \
        }                                                                 \
    }

// compute 2 output rows from pre-masked in-batch (VI,VJ) and out-batch (OI,OJ)
#define CHUNK(VI, VJ, OI, OJ)                                             \
    _Pragma("unroll")                                                     \
    for (int k = 0; k < 2; ++k) {                                         \
        F4ADD(cs0, VI[k]) F4ADD(cs1, VJ[k])                               \
        F4FMA(cs2, VI[k], VI[k]) F4FMA(cs3, VJ[k], VJ[k])                 \
        F4FMA(cs4, VI[k], VJ[k])                                          \
        float hI[4], hJ[4], hII[4], hJJ[4], hIJ[4];                       \
        HSUM_SHFL(cs0, hI)                                                \
        HSUM_SHFL(cs1, hJ)                                                \
        HSUM_SHFL(cs2, hII)                                               \
        HSUM_SHFL(cs3, hJJ)                                               \
        HSUM_SHFL(cs4, hIJ)                                               \
        float rowsum = 0.0f;                                              \
        _Pragma("unroll")                                                 \
        for (int e = 0; e < 4; ++e) {                                     \
            const float u = -hI[e] * INV_WS;                              \
            const float cross = fmaf(u, hJ[e], hIJ[e]);                   \
            const float Ivar  = fmaf(u, hI[e], hII[e]);                   \
            const float Jvar  = fmaf(-hJ[e] * INV_WS, hJ[e], hJJ[e]);     \
            float prod = Ivar * Jvar;                                     \
            float num  = cross * cross;                                   \
            if (!(prod > EPS)) { prod = 1.0f; num = 1.0f; }               \
            float inv_;                                                   \
            asm("v_rcp_f32 %0, %1" : "=v"(inv_) : "v"(prod + EPS));       \
            rowsum = fmaf(num, inv_, rowsum);                             \
        }                                                                 \
        accum += live ? rowsum : 0.0f;                                    \
        F4SUB(cs0, OI[k]) F4SUB(cs1, OJ[k])                               \
        F4FMS(cs2, OI[k], OI[k]) F4FMS(cs3, OJ[k], OJ[k])                 \
        F4FMS(cs4, OI[k], OJ[k])                                          \
    }

__launch_bounds__(NTHREADS, 2)
__global__ void lncc_pipe(const float* __restrict__ gI, const float* __restrict__ gJ,
                          float* __restrict__ part)
{
    __shared__ float wsum[4];

    const int lane = threadIdx.x & 63;
    const int band = threadIdx.x >> 6;                   // 0..3
    const int r0   = blockIdx.x * SEG;
    const int b    = blockIdx.y;
    const int c0   = band * BANDW - 4 + 4 * lane;        // own cs base col
    const float fm = (c0 >= 0 && c0 + 3 < W) ? 1.0f : 0.0f;
    const int ca   = min(max(c0, 0), W - 4);             // 16B-aligned clamp
    const bool live = (lane <= 61) && (band * BANDW + 4 * lane + 3 < W);

    const float* __restrict__ Ib = gI + (size_t)b * (H * W);
    const float* __restrict__ Jb = gJ + (size_t)b * (H * W);

    float4 cs0 = {0,0,0,0}, cs1 = {0,0,0,0}, cs2 = {0,0,0,0},
           cs3 = {0,0,0,0}, cs4 = {0,0,0,0};

    // ---- warm-up: 4 pre-masked 2-row chunks (rows r0-4 .. r0+3) ----
    float4 W0i[2], W0j[2], W1i[2], W1j[2], W2i[2], W2j[2], W3i[2], W3j[2];
    LD2(W0i, W0j, r0 - 4)
    LD2(W1i, W1j, r0 - 2)
    LD2(W2i, W2j, r0)
    LD2(W3i, W3j, r0 + 2)

    // ---- pipeline preload: in-chunks 0,1 (depth 2) + out-chunk 0 ----
    float4 I0i[2], I0j[2], I1i[2], I1j[2], I2i[2], I2j[2];
    float4 I3i[2], I3j[2], I4i[2], I4j[2], I5i[2], I5j[2];
    float4 OAi[2], OAj[2], OBi[2], OBj[2];
    LD2(I0i, I0j, r0 + 4)
    LD2(I1i, I1j, r0 + 6)
    LD2(OAi, OAj, r0 - 4)

    // warm-up accumulate (~700 cy) covers the preload latency
#define WACC(WI, WJ)                                                      \
    _Pragma("unroll")                                                     \
    for (int k = 0; k < 2; ++k) {                                         \
        F4ADD(cs0, WI[k]) F4ADD(cs1, WJ[k])                               \
        F4FMA(cs2, WI[k], WI[k]) F4FMA(cs3, WJ[k], WJ[k])                 \
        F4FMA(cs4, WI[k], WJ[k])                                          \
    }
    WACC(W0i, W0j) WACC(W1i, W1j) WACC(W2i, W2j) WACC(W3i, W3j)
#undef WACC

    float accum = 0.0f;

    // ---- 6 pipelined chunks of 2 rows (SEG = 12) ----
    // chunk c: rows r0+2c, +1; in-rows r0+2c+4 (issued 2 chunks ahead);
    // out-rows r0+2c-4 (issued 1 chunk ahead, ping-pong OA/OB).
    LD2(I2i, I2j, r0 + 8)   LD2(OBi, OBj, r0 - 2)   CHUNK(I0i, I0j, OAi, OAj)
    LD2(I3i, I3j, r0 + 10)  LD2(OAi, OAj, r0)       CHUNK(I1i, I1j, OBi, OBj)
    LD2(I4i, I4j, r0 + 12)  LD2(OBi, OBj, r0 + 2)   CHUNK(I2i, I2j, OAi, OAj)
    LD2(I5i, I5j, r0 + 14)  LD2(OAi, OAj, r0 + 4)   CHUNK(I3i, I3j, OBi, OBj)
                            LD2(OBi, OBj, r0 + 6)   CHUNK(I4i, I4j, OAi, OAj)
                                                    CHUNK(I5i, I5j, OBi, OBj)

    // ---- wave reduce -> block reduce -> one partial-store per block ----
    #pragma unroll
    for (int off = 32; off > 0; off >>= 1)
        accum += __shfl_xor(accum, off, 64);
    if (lane == 0) wsum[band] = accum;
    __syncthreads();
    if (threadIdx.x == 0)
        part[blockIdx.y * NSEG + blockIdx.x] = wsum[0] + wsum[1] + wsum[2] + wsum[3];
}

// one wave per batch image: reduce 64 block-partials, write final loss
__global__ void finalize2(const float* __restrict__ part, float* __restrict__ out) {
    const int b = threadIdx.y;              // 0..15 (one wave each)
    const int x = threadIdx.x;              // 0..63
    float v = part[b * NSEG + x];
    #pragma unroll
    for (int off = 32; off > 0; off >>= 1)
        v += __shfl_xor(v, off, 64);
    if (x == 0)
        out[b] = 1.0f - v * (1.0f / (float)(H * W));
}

extern "C" void kernel_launch(void* const* d_in, const int* in_sizes, int n_in,
                              void* d_out, int out_size, void* d_ws, size_t ws_size,
                              hipStream_t stream) {
    const float* I = (const float*)d_in[0];
    const float* J = (const float*)d_in[1];
    float* out  = (float*)d_out;
    float* part = (float*)d_ws;             // 16*64 floats, fully overwritten

    dim3 grid(NSEG, BATCH);   // 64 x 16 = 1024 blocks = 4/CU, 16 waves/CU
    lncc_pipe<<<grid, NTHREADS, 0, stream>>>(I, J, part);

    finalize2<<<1, dim3(64, BATCH), 0, stream>>>(part, out);
}

// Round 21
// 35.943 us; speedup vs baseline: 1.5155x; 1.0281x over previous
//
#include <hip/hip_runtime.h>

// LNCC loss: I,J [16,1,768,768] f32 -> out [16] f32
// R21 = R20 (scored 36.95us; kernel 40.4us, 124 VGPR, depth-2/depth-1
// register pipeline, shuffle hsum) + band-3 repacking:
// 768 = 3*248 + 24, so band 3 produced 24/248 cols at full-wave cost
// (22.5% of all wave-work for 3% of output). Now only blocks with seg%8==0
// run wave 3, whose lanes split 8 row-chunks x 8 col-groups (lane=8*rch+cg):
// one wave covers band-3 (cs cols 740..771) for EIGHT segments at the same
// per-wave cost as a main wave. Shuffle tree stays in-group for live cg<=5.
// Waves: 4096 -> 3200 (-22% work). Cross-wave LDS reduce replaced by
// per-wave partial stores (200 slots/image, all written every launch,
// no __syncthreads -> early-exit wave 3s free their slots instantly).

constexpr int BATCH = 16;
constexpr int H = 768;
constexpr int W = 768;
constexpr float INV_WS = 1.0f / 81.0f;
constexpr float EPS = 3.0590232050182579e-07f;   // exp(-15)

constexpr int SEG = 12;                   // output rows per wave task
constexpr int NSEG = H / SEG;             // 64
constexpr int BANDW = 248;                // output cols per band (bands 0-2)
constexpr int NTHREADS = 256;             // 4 waves
constexpr int PPI = 200;                  // partials per image: 64*3 main + 8 band3

#define F4ADD(a, u)    { a.x += u.x; a.y += u.y; a.z += u.z; a.w += u.w; }
#define F4SUB(a, u)    { a.x -= u.x; a.y -= u.y; a.z -= u.z; a.w -= u.w; }
#define F4FMA(a, u, v) { a.x = fmaf(u.x, v.x, a.x); a.y = fmaf(u.y, v.y, a.y); \
                         a.z = fmaf(u.z, v.z, a.z); a.w = fmaf(u.w, v.w, a.w); }
#define F4FMS(a, u, v) { a.x = fmaf(u.x, -v.x, a.x); a.y = fmaf(u.y, -v.y, a.y); \
                         a.z = fmaf(u.z, -v.z, a.z); a.w = fmaf(u.w, -v.w, a.w); }

// h[e] = sum of cs cols [c0+e, c0+e+8]; output col = c0+4+e
#define HSUM_SHFL(c, h)                                                   \
    {                                                                     \
        const float s3 = c.w;                                             \
        const float s2 = c.w + c.z;                                       \
        const float s1 = s2 + c.y;                                        \
        const float s0 = s1 + c.x;          /* own total */               \
        const float p1 = c.x + c.y;                                       \
        const float p2 = p1 + c.z;                                        \
        const float pn = __shfl_down(s0, 1, 64);                          \
        const float q0 = __shfl_down(c.x, 2, 64);                         \
        const float q1 = __shfl_down(p1, 2, 64);                          \
        const float q2 = __shfl_down(p2, 2, 64);                          \
        const float q3 = __shfl_down(s0, 2, 64);                          \
        h[0] = s0 + pn + q0;                                              \
        h[1] = s1 + pn + q1;                                              \
        h[2] = s2 + pn + q2;                                              \
        h[3] = s3 + pn + q3;                                              \
    }

// load 2 rows (rbase, rbase+1) PRE-MASKED (addr clamped, scaled by row-mask*fm)
#define LD2(NI, NJ, rbase)                                                \
    {                                                                     \
        _Pragma("unroll")                                                 \
        for (int k = 0; k < 2; ++k) {                                     \
            const int rr = (rbase) + k;                                   \
            const int rc = min(max(rr, 0), H - 1);                        \
            const float mk = (rr >= 0 && rr < H) ? fm : 0.0f;             \
            float4 ti = *(const float4*)(Ib + (size_t)rc * W + ca);       \
            float4 tj = *(const float4*)(Jb + (size_t)rc * W + ca);       \
            ti.x *= mk; ti.y *= mk; ti.z *= mk; ti.w *= mk;               \
            tj.x *= mk; tj.y *= mk; tj.z *= mk; tj.w *= mk;               \
            NI[k] = ti; NJ[k] = tj;                                       \
        }                                                                 \
    }

// compute 2 output rows from pre-masked in-batch (VI,VJ) and out-batch (OI,OJ)
#define CHUNK(VI, VJ, OI, OJ)                                             \
    _Pragma("unroll")                                                     \
    for (int k = 0; k < 2; ++k) {                                         \
        F4ADD(cs0, VI[k]) F4ADD(cs1, VJ[k])                               \
        F4FMA(cs2, VI[k], VI[k]) F4FMA(cs3, VJ[k], VJ[k])                 \
        F4FMA(cs4, VI[k], VJ[k])                                          \
        float hI[4], hJ[4], hII[4], hJJ[4], hIJ[4];                       \
        HSUM_SHFL(cs0, hI)                                                \
        HSUM_SHFL(cs1, hJ)                                                \
        HSUM_SHFL(cs2, hII)                                               \
        HSUM_SHFL(cs3, hJJ)                                               \
        HSUM_SHFL(cs4, hIJ)                                               \
        float rowsum = 0.0f;                                              \
        _Pragma("unroll")                                                 \
        for (int e = 0; e < 4; ++e) {                                     \
            const float u = -hI[e] * INV_WS;                              \
            const float cross = fmaf(u, hJ[e], hIJ[e]);                   \
            const float Ivar  = fmaf(u, hI[e], hII[e]);                   \
            const float Jvar  = fmaf(-hJ[e] * INV_WS, hJ[e], hJJ[e]);     \
            float prod = Ivar * Jvar;                                     \
            float num  = cross * cross;                                   \
            if (!(prod > EPS)) { prod = 1.0f; num = 1.0f; }               \
            float inv_;                                                   \
            asm("v_rcp_f32 %0, %1" : "=v"(inv_) : "v"(prod + EPS));       \
            rowsum = fmaf(num, inv_, rowsum);                             \
        }                                                                 \
        accum += live ? rowsum : 0.0f;                                    \
        F4SUB(cs0, OI[k]) F4SUB(cs1, OJ[k])                               \
        F4FMS(cs2, OI[k], OI[k]) F4FMS(cs3, OJ[k], OJ[k])                 \
        F4FMS(cs4, OI[k], OJ[k])                                          \
    }

__launch_bounds__(NTHREADS, 2)
__global__ void lncc_pack(const float* __restrict__ gI, const float* __restrict__ gJ,
                          float* __restrict__ part)
{
    const int lane = threadIdx.x & 63;
    const int band = threadIdx.x >> 6;                   // 0..3
    const int seg  = blockIdx.x;
    const int b    = blockIdx.y;

    int r0, c0;
    bool live;
    if (band < 3) {
        r0 = seg * SEG;
        c0 = band * BANDW - 4 + 4 * lane;                // own cs base col
        live = (lane <= 61);                             // bands 0-2 fully live
    } else {
        if (seg & 7) return;                             // wave-uniform exit
        const int rch = lane >> 3;                       // row-chunk 0..7
        const int cg  = lane & 7;                        // col-group 0..7
        r0 = (seg + rch) * SEG;                          // per-lane segment!
        c0 = 740 + 4 * cg;                               // cs cols 740..771
        live = (cg <= 5);                                // outputs 744..767
    }
    const float fm = (c0 >= 0 && c0 + 3 < W) ? 1.0f : 0.0f;
    const int ca   = min(max(c0, 0), W - 4);             // 16B-aligned clamp

    const float* __restrict__ Ib = gI + (size_t)b * (H * W);
    const float* __restrict__ Jb = gJ + (size_t)b * (H * W);

    float4 cs0 = {0,0,0,0}, cs1 = {0,0,0,0}, cs2 = {0,0,0,0},
           cs3 = {0,0,0,0}, cs4 = {0,0,0,0};

    // ---- warm-up: 4 pre-masked 2-row chunks (rows r0-4 .. r0+3) ----
    float4 W0i[2], W0j[2], W1i[2], W1j[2], W2i[2], W2j[2], W3i[2], W3j[2];
    LD2(W0i, W0j, r0 - 4)
    LD2(W1i, W1j, r0 - 2)
    LD2(W2i, W2j, r0)
    LD2(W3i, W3j, r0 + 2)

    // ---- pipeline preload: in-chunks 0,1 (depth 2) + out-chunk 0 ----
    float4 I0i[2], I0j[2], I1i[2], I1j[2], I2i[2], I2j[2];
    float4 I3i[2], I3j[2], I4i[2], I4j[2], I5i[2], I5j[2];
    float4 OAi[2], OAj[2], OBi[2], OBj[2];
    LD2(I0i, I0j, r0 + 4)
    LD2(I1i, I1j, r0 + 6)
    LD2(OAi, OAj, r0 - 4)

    // warm-up accumulate (~700 cy) covers the preload latency
#define WACC(WI, WJ)                                                      \
    _Pragma("unroll")                                                     \
    for (int k = 0; k < 2; ++k) {                                         \
        F4ADD(cs0, WI[k]) F4ADD(cs1, WJ[k])                               \
        F4FMA(cs2, WI[k], WI[k]) F4FMA(cs3, WJ[k], WJ[k])                 \
        F4FMA(cs4, WI[k], WJ[k])                                          \
    }
    WACC(W0i, W0j) WACC(W1i, W1j) WACC(W2i, W2j) WACC(W3i, W3j)
#undef WACC

    float accum = 0.0f;

    // ---- 6 pipelined chunks of 2 rows (SEG = 12) ----
    LD2(I2i, I2j, r0 + 8)   LD2(OBi, OBj, r0 - 2)   CHUNK(I0i, I0j, OAi, OAj)
    LD2(I3i, I3j, r0 + 10)  LD2(OAi, OAj, r0)       CHUNK(I1i, I1j, OBi, OBj)
    LD2(I4i, I4j, r0 + 12)  LD2(OBi, OBj, r0 + 2)   CHUNK(I2i, I2j, OAi, OAj)
    LD2(I5i, I5j, r0 + 14)  LD2(OAi, OAj, r0 + 4)   CHUNK(I3i, I3j, OBi, OBj)
                            LD2(OBi, OBj, r0 + 6)   CHUNK(I4i, I4j, OAi, OAj)
                                                    CHUNK(I5i, I5j, OBi, OBj)

    // ---- wave reduce -> one partial-store per wave (no LDS, no barrier) ----
    #pragma unroll
    for (int off = 32; off > 0; off >>= 1)
        accum += __shfl_xor(accum, off, 64);
    if (lane == 0) {
        if (band < 3)
            part[b * PPI + seg * 3 + band] = accum;      // slots 0..191
        else
            part[b * PPI + 192 + (seg >> 3)] = accum;    // slots 192..199
    }
}

// one wave per batch image: reduce 200 wave-partials, write final loss
__global__ void finalize2(const float* __restrict__ part, float* __restrict__ out) {
    const int b = threadIdx.y;              // 0..15 (one wave each)
    const int x = threadIdx.x;              // 0..63
    const int base = b * PPI;
    float v = part[base + x] + part[base + 64 + x] + part[base + 128 + x];
    if (x < 8) v += part[base + 192 + x];
    #pragma unroll
    for (int off = 32; off > 0; off >>= 1)
        v += __shfl_xor(v, off, 64);
    if (x == 0)
        out[b] = 1.0f - v * (1.0f / (float)(H * W));
}

extern "C" void kernel_launch(void* const* d_in, const int* in_sizes, int n_in,
                              void* d_out, int out_size, void* d_ws, size_t ws_size,
                              hipStream_t stream) {
    const float* I = (const float*)d_in[0];
    const float* J = (const float*)d_in[1];
    float* out  = (float*)d_out;
    float* part = (float*)d_ws;             // 16*200 floats, all written each launch

    dim3 grid(NSEG, BATCH);   // 64 x 16 = 1024 blocks; 3200 working waves
    lncc_pack<<<grid, NTHREADS, 0, stream>>>(I, J, part);

    finalize2<<<1, dim3(64, BATCH), 0, stream>>>(part, out);
}

// Round 22
// 35.247 us; speedup vs baseline: 1.5454x; 1.0197x over previous
//
#include <hip/hip_runtime.h>

// LNCC loss: I,J [16,1,768,768] f32 -> out [16] f32
// R22 = R21 (scored 35.94us; 112 VGPR, band-3 packing, depth-2 in-prefetch)
// + depth-2 OUT-prefetch: third O buffer (OC), 3-way rotation, so chunks 2-5
// get ~2-chunk (~1100cy) cover on the out-row reloads (previously depth-1
// ~540cy vs L2-miss/L3 latency 400-900cy — the last exposed wait).
// R18 tested {O=register-retention, I-depth-1} = 47.7us; R17 tested
// {O-depth-1, I-depth-2} = 40.2us; this is the untested {I-depth-2,
// O-depth-2} cell. Register budget is the risk: est. 120-132 vs the 128
// cap/cliff; launch_bounds(256,2) keeps cap 128 (minor cold-reg spill
// preferred over occupancy drop; WRITE_SIZE is the tell).

constexpr int BATCH = 16;
constexpr int H = 768;
constexpr int W = 768;
constexpr float INV_WS = 1.0f / 81.0f;
constexpr float EPS = 3.0590232050182579e-07f;   // exp(-15)

constexpr int SEG = 12;                   // output rows per wave task
constexpr int NSEG = H / SEG;             // 64
constexpr int BANDW = 248;                // output cols per band (bands 0-2)
constexpr int NTHREADS = 256;             // 4 waves
constexpr int PPI = 200;                  // partials per image: 64*3 main + 8 band3

#define F4ADD(a, u)    { a.x += u.x; a.y += u.y; a.z += u.z; a.w += u.w; }
#define F4SUB(a, u)    { a.x -= u.x; a.y -= u.y; a.z -= u.z; a.w -= u.w; }
#define F4FMA(a, u, v) { a.x = fmaf(u.x, v.x, a.x); a.y = fmaf(u.y, v.y, a.y); \
                         a.z = fmaf(u.z, v.z, a.z); a.w = fmaf(u.w, v.w, a.w); }
#define F4FMS(a, u, v) { a.x = fmaf(u.x, -v.x, a.x); a.y = fmaf(u.y, -v.y, a.y); \
                         a.z = fmaf(u.z, -v.z, a.z); a.w = fmaf(u.w, -v.w, a.w); }

// h[e] = sum of cs cols [c0+e, c0+e+8]; output col = c0+4+e
#define HSUM_SHFL(c, h)                                                   \
    {                                                                     \
        const float s3 = c.w;                                             \
        const float s2 = c.w + c.z;                                       \
        const float s1 = s2 + c.y;                                        \
        const float s0 = s1 + c.x;          /* own total */               \
        const float p1 = c.x + c.y;                                       \
        const float p2 = p1 + c.z;                                        \
        const float pn = __shfl_down(s0, 1, 64);                          \
        const float q0 = __shfl_down(c.x, 2, 64);                         \
        const float q1 = __shfl_down(p1, 2, 64);                          \
        const float q2 = __shfl_down(p2, 2, 64);                          \
        const float q3 = __shfl_down(s0, 2, 64);                          \
        h[0] = s0 + pn + q0;                                              \
        h[1] = s1 + pn + q1;                                              \
        h[2] = s2 + pn + q2;                                              \
        h[3] = s3 + pn + q3;                                              \
    }

// load 2 rows (rbase, rbase+1) PRE-MASKED (addr clamped, scaled by row-mask*fm)
#define LD2(NI, NJ, rbase)                                                \
    {                                                                     \
        _Pragma("unroll")                                                 \
        for (int k = 0; k < 2; ++k) {                                     \
            const int rr = (rbase) + k;                                   \
            const int rc = min(max(rr, 0), H - 1);                        \
            const float mk = (rr >= 0 && rr < H) ? fm : 0.0f;             \
            float4 ti = *(const float4*)(Ib + (size_t)rc * W + ca);       \
            float4 tj = *(const float4*)(Jb + (size_t)rc * W + ca);       \
            ti.x *= mk; ti.y *= mk; ti.z *= mk; ti.w *= mk;               \
            tj.x *= mk; tj.y *= mk; tj.z *= mk; tj.w *= mk;               \
            NI[k] = ti; NJ[k] = tj;                                       \
        }                                                                 \
    }

// compute 2 output rows from pre-masked in-batch (VI,VJ) and out-batch (OI,OJ)
#define CHUNK(VI, VJ, OI, OJ)                                             \
    _Pragma("unroll")                                                     \
    for (int k = 0; k < 2; ++k) {                                         \
        F4ADD(cs0, VI[k]) F4ADD(cs1, VJ[k])                               \
        F4FMA(cs2, VI[k], VI[k]) F4FMA(cs3, VJ[k], VJ[k])                 \
        F4FMA(cs4, VI[k], VJ[k])                                          \
        float hI[4], hJ[4], hII[4], hJJ[4], hIJ[4];                       \
        HSUM_SHFL(cs0, hI)                                                \
        HSUM_SHFL(cs1, hJ)                                                \
        HSUM_SHFL(cs2, hII)                                               \
        HSUM_SHFL(cs3, hJJ)                                               \
        HSUM_SHFL(cs4, hIJ)                                               \
        float rowsum = 0.0f;                                              \
        _Pragma("unroll")                                                 \
        for (int e = 0; e < 4; ++e) {                                     \
            const float u = -hI[e] * INV_WS;                              \
            const float cross = fmaf(u, hJ[e], hIJ[e]);                   \
            const float Ivar  = fmaf(u, hI[e], hII[e]);                   \
            const float Jvar  = fmaf(-hJ[e] * INV_WS, hJ[e], hJJ[e]);     \
            float prod = Ivar * Jvar;                                     \
            float num  = cross * cross;                                   \
            if (!(prod > EPS)) { prod = 1.0f; num = 1.0f; }               \
            float inv_;                                                   \
            asm("v_rcp_f32 %0, %1" : "=v"(inv_) : "v"(prod + EPS));       \
            rowsum = fmaf(num, inv_, rowsum);                             \
        }                                                                 \
        accum += live ? rowsum : 0.0f;                                    \
        F4SUB(cs0, OI[k]) F4SUB(cs1, OJ[k])                               \
        F4FMS(cs2, OI[k], OI[k]) F4FMS(cs3, OJ[k], OJ[k])                 \
        F4FMS(cs4, OI[k], OJ[k])                                          \
    }

__launch_bounds__(NTHREADS, 2)
__global__ void lncc_o2(const float* __restrict__ gI, const float* __restrict__ gJ,
                        float* __restrict__ part)
{
    const int lane = threadIdx.x & 63;
    const int band = threadIdx.x >> 6;                   // 0..3
    const int seg  = blockIdx.x;
    const int b    = blockIdx.y;

    int r0, c0;
    bool live;
    if (band < 3) {
        r0 = seg * SEG;
        c0 = band * BANDW - 4 + 4 * lane;                // own cs base col
        live = (lane <= 61);                             // bands 0-2 fully live
    } else {
        if (seg & 7) return;                             // wave-uniform exit
        const int rch = lane >> 3;                       // row-chunk 0..7
        const int cg  = lane & 7;                        // col-group 0..7
        r0 = (seg + rch) * SEG;                          // per-lane segment
        c0 = 740 + 4 * cg;                               // cs cols 740..771
        live = (cg <= 5);                                // outputs 744..767
    }
    const float fm = (c0 >= 0 && c0 + 3 < W) ? 1.0f : 0.0f;
    const int ca   = min(max(c0, 0), W - 4);             // 16B-aligned clamp

    const float* __restrict__ Ib = gI + (size_t)b * (H * W);
    const float* __restrict__ Jb = gJ + (size_t)b * (H * W);

    float4 cs0 = {0,0,0,0}, cs1 = {0,0,0,0}, cs2 = {0,0,0,0},
           cs3 = {0,0,0,0}, cs4 = {0,0,0,0};

    // ---- warm-up: 4 pre-masked 2-row chunks (rows r0-4 .. r0+3) ----
    float4 W0i[2], W0j[2], W1i[2], W1j[2], W2i[2], W2j[2], W3i[2], W3j[2];
    LD2(W0i, W0j, r0 - 4)
    LD2(W1i, W1j, r0 - 2)
    LD2(W2i, W2j, r0)
    LD2(W3i, W3j, r0 + 2)

    // ---- pipeline preload: in-chunks 0,1 (depth 2) + out-chunk 0 ----
    float4 I0i[2], I0j[2], I1i[2], I1j[2], I2i[2], I2j[2];
    float4 I3i[2], I3j[2], I4i[2], I4j[2], I5i[2], I5j[2];
    float4 OAi[2], OAj[2], OBi[2], OBj[2], OCi[2], OCj[2];
    LD2(I0i, I0j, r0 + 4)
    LD2(I1i, I1j, r0 + 6)
    LD2(OAi, OAj, r0 - 4)

    // warm-up accumulate (~700 cy) covers the preload latency
#define WACC(WI, WJ)                                                      \
    _Pragma("unroll")                                                     \
    for (int k = 0; k < 2; ++k) {                                         \
        F4ADD(cs0, WI[k]) F4ADD(cs1, WJ[k])                               \
        F4FMA(cs2, WI[k], WI[k]) F4FMA(cs3, WJ[k], WJ[k])                 \
        F4FMA(cs4, WI[k], WJ[k])                                          \
    }
    WACC(W0i, W0j) WACC(W1i, W1j) WACC(W2i, W2j) WACC(W3i, W3j)
#undef WACC

    float accum = 0.0f;

    // ---- 6 pipelined chunks of 2 rows (SEG = 12) ----
    // in-loads 2 chunks ahead (I0..I5); out-loads now ALSO ~2 chunks ahead
    // via 3-way O rotation (OA preload, OB/OC at iter0, then one O per iter).
    LD2(I2i, I2j, r0 + 8)   LD2(OBi, OBj, r0 - 2)
                            LD2(OCi, OCj, r0)       CHUNK(I0i, I0j, OAi, OAj)
    LD2(I3i, I3j, r0 + 10)  LD2(OAi, OAj, r0 + 2)   CHUNK(I1i, I1j, OBi, OBj)
    LD2(I4i, I4j, r0 + 12)  LD2(OBi, OBj, r0 + 4)   CHUNK(I2i, I2j, OCi, OCj)
    LD2(I5i, I5j, r0 + 14)  LD2(OCi, OCj, r0 + 6)   CHUNK(I3i, I3j, OAi, OAj)
                                                    CHUNK(I4i, I4j, OBi, OBj)
                                                    CHUNK(I5i, I5j, OCi, OCj)

    // ---- wave reduce -> one partial-store per wave (no LDS, no barrier) ----
    #pragma unroll
    for (int off = 32; off > 0; off >>= 1)
        accum += __shfl_xor(accum, off, 64);
    if (lane == 0) {
        if (band < 3)
            part[b * PPI + seg * 3 + band] = accum;      // slots 0..191
        else
            part[b * PPI + 192 + (seg >> 3)] = accum;    // slots 192..199
    }
}

// one wave per batch image: reduce 200 wave-partials, write final loss
__global__ void finalize2(const float* __restrict__ part, float* __restrict__ out) {
    const int b = threadIdx.y;              // 0..15 (one wave each)
    const int x = threadIdx.x;              // 0..63
    const int base = b * PPI;
    float v = part[base + x] + part[base + 64 + x] + part[base + 128 + x];
    if (x < 8) v += part[base + 192 + x];
    #pragma unroll
    for (int off = 32; off > 0; off >>= 1)
        v += __shfl_xor(v, off, 64);
    if (x == 0)
        out[b] = 1.0f - v * (1.0f / (float)(H * W));
}

extern "C" void kernel_launch(void* const* d_in, const int* in_sizes, int n_in,
                              void* d_out, int out_size, void* d_ws, size_t ws_size,
                              hipStream_t stream) {
    const float* I = (const float*)d_in[0];
    const float* J = (const float*)d_in[1];
    float* out  = (float*)d_out;
    float* part = (float*)d_ws;             // 16*200 floats, all written each launch

    dim3 grid(NSEG, BATCH);   // 64 x 16 = 1024 blocks; 3200 working waves
    lncc_o2<<<grid, NTHREADS, 0, stream>>>(I, J, part);

    finalize2<<<1, dim3(64, BATCH), 0, stream>>>(part, out);
}